// Round 4
// baseline (379.502 us; speedup 1.0000x reference)
//
#include <hip/hip_runtime.h>
#include <stdint.h>

typedef unsigned long long u64;
typedef unsigned int u32;
typedef float f32x4 __attribute__((ext_vector_type(4)));

#define T_STEPS 100
#define NNEUR 256
#define NBF 2048                 // B*F = 32*64
#define NELEM (NBF * NNEUR)      // 524288 per time step
#define T_PER_BLK 4

// ---- Threefry-2x32, 20 rounds, exactly as jax/_src/prng.py ----
__device__ __forceinline__ void tf2x32(u32 k0, u32 k1, u32& x0, u32& x1) {
  u32 k2 = k0 ^ k1 ^ 0x1BD11BDAu;
  x0 += k0; x1 += k1;
#define TFR(r) { x0 += x1; x1 = (x1 << (r)) | (x1 >> (32 - (r))); x1 ^= x0; }
  TFR(13) TFR(15) TFR(26) TFR(6)
  x0 += k1; x1 += k2 + 1u;
  TFR(17) TFR(29) TFR(16) TFR(24)
  x0 += k2; x1 += k0 + 2u;
  TFR(13) TFR(15) TFR(26) TFR(6)
  x0 += k0; x1 += k1 + 3u;
  TFR(17) TFR(29) TFR(16) TFR(24)
  x0 += k1; x1 += k2 + 4u;
  TFR(13) TFR(15) TFR(26) TFR(6)
  x0 += k2; x1 += k0 + 5u;
#undef TFR
}

__device__ __forceinline__ u32 rotl32(u32 x, int r) {
  return __builtin_amdgcn_alignbit(x, x, 32 - r);   // v_alignbit_b32
}

// thr9[i] = ceil(p_i * 2^23) << 9 : integer threshold for (x0^x1) < thr9
// (exact: (m>>9) < T  <=>  m < T<<9; T <= ceil(0.1*2^23) so no overflow)
// Block 0 also zeroes the occ accumulator (replaces the memset node).
__global__ void __launch_bounds__(256) kern_p(
    const float* __restrict__ x, const float* __restrict__ c,
    const float* __restrict__ w, const float* __restrict__ a,
    u32* __restrict__ thr9, u32* __restrict__ occ32) {
  int idx = blockIdx.x * 256 + threadIdx.x;
  int n = idx & 255, bf = idx >> 8;
  float d = x[bf] - c[n];
  float denom = (2.0f * w[n]) * w[n];
  float q = -(d * d) / denom;
  float e = (float)exp((double)q);
  float p = (e * a[n]) * 0.1f;
  thr9[idx] = ((u32)ceilf(p * 8388608.0f)) << 9;
  if (blockIdx.x == 0 && threadIdx.x < 200) {
    ((uint4*)occ32)[threadIdx.x] = make_uint4(0u, 0u, 0u, 0u);
  }
}

// Stage A: thread owns (bf, octet of 32 neurons) and processes 4 t-steps;
// thresholds loaded once into 32 VGPRs, 32 fully-unrolled threefry chains
// per t, integer-threshold compare, bits packed into one u32 per t.
__global__ void __launch_bounds__(256, 4) kern_bits2(
    const u32* __restrict__ thr9,
    const int* __restrict__ seedp,
    u32* __restrict__ cmp32,        // [bf][t][8]
    u32* __restrict__ occ32) {      // [t][8] OR-reduced over bf
  const int t0 = blockIdx.x * T_PER_BLK;
  const int g = blockIdx.y;        // 0..63 (32 bf each)
  const int tid = threadIdx.x;
  const int oct = tid & 7;
  const int bfl = tid >> 3;        // 0..31
  const int bf = g * 32 + bfl;
  const u32 seed = (u32)seedp[0];
  const u32 base_i = (u32)(bf * 256 + oct * 32);

  // 32 pre-shifted thresholds resident in VGPRs (loaded once for 4 t-steps)
  u32 th[32];
  const uint4* tp = (const uint4*)(thr9 + base_i);
#pragma unroll
  for (int q = 0; q < 8; ++q) {
    uint4 v = tp[q];
    th[4*q] = v.x; th[4*q+1] = v.y; th[4*q+2] = v.z; th[4*q+3] = v.w;
  }

  u32* cmp_base = cmp32 + (u32)bf * (T_STEPS * 8) + oct;

#pragma unroll 1
  for (int tt = 0; tt < T_PER_BLK; ++tt) {
    const int t = t0 + tt;
    // k_t = fold_in(key(seed), t) = threefry2x32(key=(0,seed), x=(0,t))
    u32 K0 = 0u, K1 = (u32)t;
    tf2x32(0u, seed, K0, K1);
    const u32 K2 = K0 ^ K1 ^ 0x1BD11BDAu;
    const u32 I10 = K1;
    const u32 I11 = K2 + 1u;
    const u32 I20 = K2;
    const u32 I21 = K0 + 2u;
    const u32 I30 = K0;
    const u32 I31 = K1 + 3u;
    const u32 I40 = K1;
    const u32 I41 = K2 + 4u;
    const u32 I50 = K2;
    const u32 I51 = K0 + 5u;

    const u32 x1base = base_i + K1;     // x1 pre-whitened
    const u32 x0base = x1base + K0;     // x0 after pre-add + first mix add
    u32 word = 0u;
#pragma unroll
    for (int k = 31; k >= 0; --k) {
      u32 x1 = x1base + (u32)k;
      u32 x0 = x0base + (u32)k;
      x1 = rotl32(x1, 13); x1 ^= x0;    // finish round 1
#define QR(r) { x0 += x1; x1 = rotl32(x1, r); x1 ^= x0; }
      QR(15) QR(26) QR(6)
      x0 += I10; x1 += I11;
      QR(17) QR(29) QR(16) QR(24)
      x0 += I20; x1 += I21;
      QR(13) QR(15) QR(26) QR(6)
      x0 += I30; x1 += I31;
      QR(17) QR(29) QR(16) QR(24)
      x0 += I40; x1 += I41;
      QR(13) QR(15) QR(26) QR(6)
      x0 += I50; x1 += I51;
#undef QR
      word = (word << 1) | ((x0 ^ x1) < th[k] ? 1u : 0u);
    }

    cmp_base[t * 8] = word;

    // OR across the 8 bf-values in this wave (lanes differ in bits 3..5)
    u32 o = word;
    o |= (u32)__shfl_xor((int)o, 8, 64);
    o |= (u32)__shfl_xor((int)o, 16, 64);
    o |= (u32)__shfl_xor((int)o, 32, 64);
    if ((tid & 63) < 8) atomicOr(&occ32[t * 8 + oct], o);
  }
}

// Stage B+C fused: per-bf block stages its cmp slice into registers, re-runs
// the 100-step refractory recurrence from occ in LDS, ANDs cmp with can,
// writes float4 output with nontemporal stores.
__global__ void __launch_bounds__(256) kern_out2(
    const u32* __restrict__ cmp32,   // [bf][t][8]
    const u32* __restrict__ occ32,   // [t][8]
    const float* __restrict__ ref0,
    float* __restrict__ out) {
  __shared__ u32 s_can[T_STEPS * 8];
  __shared__ u32 s[T_STEPS * 8];
  const int bf = blockIdx.x;
  const int tid = threadIdx.x;

  // stage this bf's cmp slice (3200 B) into registers, coalesced uint4
  uint4 myc = make_uint4(0u, 0u, 0u, 0u);
  if (tid < 200) myc = ((const uint4*)(cmp32 + (u64)bf * (T_STEPS * 8)))[tid];

  // occ into LDS (s reused as occ buffer for the recurrence)
  if (tid < 200) ((uint4*)s)[tid] = ((const uint4*)occ32)[tid];
  __syncthreads();

  {
    const int n = tid, lane = n & 63, v = n >> 6;
    float ref = ref0[n];
    for (int t = 0; t < T_STEPS; ++t) {
      bool can = (ref == 0.0f);
      u64 cm = __ballot(can);
      if (lane == 0) {
        s_can[t * 8 + v * 2]     = (u32)cm;
        s_can[t * 8 + v * 2 + 1] = (u32)(cm >> 32);
      }
      bool occb = (s[t * 8 + (n >> 5)] >> (n & 31)) & 1u;
      bool occurred = can && occb;
      ref = fmaxf(ref - 1.0f, 0.0f) + (occurred ? 2.0f : 0.0f);
    }
  }
  __syncthreads();

  if (tid < 200) {
    uint4 cn = ((const uint4*)s_can)[tid];
    uint4 r;
    r.x = myc.x & cn.x; r.y = myc.y & cn.y;
    r.z = myc.z & cn.z; r.w = myc.w & cn.w;
    ((uint4*)s)[tid] = r;
  }
  __syncthreads();

  f32x4* outv = (f32x4*)(out + (u64)bf * (NNEUR * T_STEPS));
#pragma unroll
  for (int kk = 0; kk < 25; ++kk) {
    int q = tid + 256 * kk;          // float4 index within slice (6400 total)
    int e = q * 4;
    f32x4 val;
#pragma unroll
    for (int j = 0; j < 4; ++j) {
      int ee = e + j;
      int n = ee / 100;
      int t = ee - n * 100;
      val[j] = (float)((s[t * 8 + (n >> 5)] >> (n & 31)) & 1u);
    }
    __builtin_nontemporal_store(val, &outv[q]);
  }
}

// ---------------- fallback path (ws too small): round-1 working scheme ----
__global__ void __launch_bounds__(256) kern_bits_fb(
    const float* __restrict__ x, const float* __restrict__ c,
    const float* __restrict__ w, const float* __restrict__ a,
    const int* __restrict__ seedp,
    float* __restrict__ outf,
    u64* __restrict__ occ64) {
  const int t = blockIdx.x;
  const int chunk = blockIdx.y;
  const int lane = threadIdx.x & 63;
  const int v = threadIdx.x >> 6;
  const int n = v * 64 + lane;
  const u32 seed = (u32)seedp[0];
  u32 kt0 = 0u, kt1 = (u32)t;
  tf2x32(0u, seed, kt0, kt1);
  float cn = c[n], wn = w[n], an = a[n];
  bool occ = false;
  for (int j = 0; j < 64; ++j) {
    int bf = chunk * 64 + j;
    u32 i = (u32)(bf * 256 + n);
    u32 b0 = 0u, b1 = i;
    tf2x32(kt0, kt1, b0, b1);
    u32 bits = b0 ^ b1;
    float r = __uint_as_float((bits >> 9) | 0x3F800000u) - 1.0f;
    float d = x[bf] - cn;
    float denom = (2.0f * wn) * wn;
    float q = -(d * d) / denom;
    float pv = ((float)exp((double)q) * an) * 0.1f;
    bool cm = r < pv;
    occ |= cm;
    outf[(u64)bf * (NNEUR * T_STEPS) + (u64)n * T_STEPS + t] = cm ? 1.0f : 0.0f;
  }
  u64 om = __ballot(occ);
  if (lane == 0) atomicOr(&occ64[t * 4 + v], om);
}

__global__ void __launch_bounds__(256) kern_rec(
    const float* __restrict__ ref0,
    const u64* __restrict__ occ64,
    u64* __restrict__ can64) {
  int n = threadIdx.x;
  int lane = n & 63, v = n >> 6;
  float ref = ref0[n];
  for (int t = 0; t < T_STEPS; ++t) {
    bool can = (ref == 0.0f);
    u64 cm = __ballot(can);
    if (lane == 0) can64[t * 4 + v] = cm;
    bool occb = (occ64[t * 4 + v] >> lane) & 1ull;
    bool occurred = can && occb;
    ref = fmaxf(ref - 1.0f, 0.0f) + (occurred ? 2.0f : 0.0f);
  }
}

__global__ void __launch_bounds__(256) kern_mask(
    const u32* __restrict__ can32, float* __restrict__ out) {
  u64 q = (u64)blockIdx.x * 256 + threadIdx.x;
  float4* ov = (float4*)out;
  float4 vx = ov[q];
  u32 local = (u32)((q * 4) % (NNEUR * T_STEPS));
  float* vp = (float*)&vx;
#pragma unroll
  for (int j = 0; j < 4; ++j) {
    u32 le = local + j;
    u32 n = le / 100;
    u32 t = le - n * 100;
    u32 bit = (can32[t * 8 + (n >> 5)] >> (n & 31)) & 1u;
    vp[j] = bit ? vp[j] : 0.0f;
  }
  ov[q] = vx;
}

extern "C" void kernel_launch(void* const* d_in, const int* in_sizes, int n_in,
                              void* d_out, int out_size, void* d_ws, size_t ws_size,
                              hipStream_t stream) {
  const float* x  = (const float*)d_in[0];
  const float* c  = (const float*)d_in[1];
  const float* w  = (const float*)d_in[2];
  const float* a  = (const float*)d_in[3];
  const float* r0 = (const float*)d_in[4];
  const int* seed = (const int*)d_in[5];
  float* out = (float*)d_out;

  const size_t P_BYTES   = (size_t)NELEM * 4;                    // 2 MB thresholds
  const size_t CMP_BYTES = (size_t)NBF * T_STEPS * 4 * 8;        // 6.55 MB
  const size_t OCC_BYTES = (size_t)T_STEPS * 4 * 8;              // 3200 B
  const bool full = ws_size >= P_BYTES + CMP_BYTES + 2 * OCC_BYTES;

  uint8_t* wsb = (uint8_t*)d_ws;

  if (full) {
    u32* thr   = (u32*)wsb;
    u32* cmp   = (u32*)(wsb + P_BYTES);
    u32* occ   = (u32*)(wsb + P_BYTES + CMP_BYTES);
    kern_p<<<NELEM / 256, 256, 0, stream>>>(x, c, w, a, thr, occ);
    kern_bits2<<<dim3(T_STEPS / T_PER_BLK, 64), 256, 0, stream>>>(thr, seed, cmp, occ);
    kern_out2<<<NBF, 256, 0, stream>>>(cmp, occ, r0, out);
  } else {
    u64* occ = (u64*)wsb;
    u64* can = (u64*)(wsb + OCC_BYTES);
    hipMemsetAsync(occ, 0, OCC_BYTES, stream);
    kern_bits_fb<<<dim3(T_STEPS, 32), 256, 0, stream>>>(x, c, w, a, seed, out, occ);
    kern_rec<<<1, 256, 0, stream>>>(r0, occ, can);
    kern_mask<<<(out_size / 4) / 256, 256, 0, stream>>>((const u32*)can, out);
  }
}

// Round 5
// 335.996 us; speedup vs baseline: 1.1295x; 1.1295x over previous
//
#include <hip/hip_runtime.h>
#include <stdint.h>

typedef unsigned long long u64;
typedef unsigned int u32;
typedef float f32x4 __attribute__((ext_vector_type(4)));

#define T_STEPS 100
#define NNEUR 256
#define NBF 2048                 // B*F = 32*64
#define NELEM (NBF * NNEUR)      // 524288 per time step

// ---- Threefry-2x32, 20 rounds, exactly as jax/_src/prng.py ----
__device__ __forceinline__ void tf2x32(u32 k0, u32 k1, u32& x0, u32& x1) {
  u32 k2 = k0 ^ k1 ^ 0x1BD11BDAu;
  x0 += k0; x1 += k1;
#define TFR(r) { x0 += x1; x1 = (x1 << (r)) | (x1 >> (32 - (r))); x1 ^= x0; }
  TFR(13) TFR(15) TFR(26) TFR(6)
  x0 += k1; x1 += k2 + 1u;
  TFR(17) TFR(29) TFR(16) TFR(24)
  x0 += k2; x1 += k0 + 2u;
  TFR(13) TFR(15) TFR(26) TFR(6)
  x0 += k0; x1 += k1 + 3u;
  TFR(17) TFR(29) TFR(16) TFR(24)
  x0 += k1; x1 += k2 + 4u;
  TFR(13) TFR(15) TFR(26) TFR(6)
  x0 += k2; x1 += k0 + 5u;
#undef TFR
}

__device__ __forceinline__ u32 rotl32(u32 x, int r) {
  return __builtin_amdgcn_alignbit(x, x, 32 - r);   // v_alignbit_b32
}

// thr9[i] = ceil(p_i * 2^23) << 9 : integer threshold for (x0^x1) < thr9
// (exact: (m>>9) < T  <=>  m < T<<9; T <= ceil(0.1*2^23) so no overflow)
// Block 0 also zeroes the occ accumulator (replaces the memset node).
__global__ void __launch_bounds__(256) kern_p(
    const float* __restrict__ x, const float* __restrict__ c,
    const float* __restrict__ w, const float* __restrict__ a,
    u32* __restrict__ thr9, u32* __restrict__ occ32) {
  int idx = blockIdx.x * 256 + threadIdx.x;
  int n = idx & 255, bf = idx >> 8;
  float d = x[bf] - c[n];
  float denom = (2.0f * w[n]) * w[n];
  float q = -(d * d) / denom;
  float e = (float)exp((double)q);
  float p = (e * a[n]) * 0.1f;
  thr9[idx] = ((u32)ceilf(p * 8388608.0f)) << 9;
  if (blockIdx.x == 0 && threadIdx.x < 200) {
    ((uint4*)occ32)[threadIdx.x] = make_uint4(0u, 0u, 0u, 0u);
  }
}

// Stage A: thread owns (bf, 16 neurons) -> th[16] + ~20 temps stays under the
// 64-VGPR cap, so __launch_bounds__(256,8) gives 8 waves/SIMD (2x latency
// hiding vs round 2-4). Key schedule forced to SALU via readfirstlane(seed).
__global__ void __launch_bounds__(256, 8) kern_bits3(
    const u32* __restrict__ thr9,
    const int* __restrict__ seedp,
    u32* __restrict__ cmp32,        // [bf][t][8]
    u32* __restrict__ occ32) {      // [t][8] OR-reduced over bf
  const int t = blockIdx.x;
  const int g = blockIdx.y;        // 0..127 (16 bf each)
  const int tid = threadIdx.x;
  const int hoct = tid & 15;       // half-octet: 16 neurons
  const int bfl = tid >> 4;        // 0..15
  const int bf = g * 16 + bfl;
  const u32 seed = (u32)__builtin_amdgcn_readfirstlane((int)seedp[0]);

  // k_t = fold_in(key(seed), t) = threefry2x32(key=(0,seed), x=(0,t)) -- SALU
  u32 K0 = 0u, K1 = (u32)t;
  tf2x32(0u, seed, K0, K1);
  const u32 K2 = K0 ^ K1 ^ 0x1BD11BDAu;
  const u32 I10 = K1;
  const u32 I11 = K2 + 1u;
  const u32 I20 = K2;
  const u32 I21 = K0 + 2u;
  const u32 I30 = K0;
  const u32 I31 = K1 + 3u;
  const u32 I40 = K1;
  const u32 I41 = K2 + 4u;
  const u32 I50 = K2;
  const u32 I51 = K0 + 5u;

  const u32 base_i = (u32)(bf * 256 + hoct * 16);

  // 16 pre-shifted thresholds resident in VGPRs
  u32 th[16];
  const uint4* tp = (const uint4*)(thr9 + base_i);
#pragma unroll
  for (int q = 0; q < 4; ++q) {
    uint4 v = tp[q];
    th[4*q] = v.x; th[4*q+1] = v.y; th[4*q+2] = v.z; th[4*q+3] = v.w;
  }

  const u32 x1base = base_i + K1;       // x1 pre-whitened
  const u32 x0base = x1base + K0;       // x0 after pre-add + first mix add
  u32 word = 0u;                        // 16 compare bits
#pragma unroll
  for (int k = 15; k >= 0; --k) {
    u32 x1 = x1base + (u32)k;
    u32 x0 = x0base + (u32)k;
    x1 = rotl32(x1, 13); x1 ^= x0;      // finish round 1
#define QR(r) { x0 += x1; x1 = rotl32(x1, r); x1 ^= x0; }
    QR(15) QR(26) QR(6)
    x0 += I10; x1 += I11;
    QR(17) QR(29) QR(16) QR(24)
    x0 += I20; x1 += I21;
    QR(13) QR(15) QR(26) QR(6)
    x0 += I30; x1 += I31;
    QR(17) QR(29) QR(16) QR(24)
    x0 += I40; x1 += I41;
    QR(13) QR(15) QR(26) QR(6)
    x0 += I50; x1 += I51;
#undef QR
    word = (word << 1) | ((x0 ^ x1) < th[k] ? 1u : 0u);
  }

  // merge 16-bit halves into full 32-neuron words (even hoct = low half)
  u32 partner = (u32)__shfl_xor((int)word, 1, 64);
  if (!(hoct & 1)) {
    u32 word32 = word | (partner << 16);
    cmp32[(u32)bf * (T_STEPS * 8) + (u32)t * 8 + (hoct >> 1)] = word32;
  }

  // OR across the 4 bf in this wave (lane bits 4..5), then merge halves
  u32 o = word;
  o |= (u32)__shfl_xor((int)o, 16, 64);
  o |= (u32)__shfl_xor((int)o, 32, 64);
  u32 op = (u32)__shfl_xor((int)o, 1, 64);
  if ((tid & 63) < 16 && !(hoct & 1)) {
    atomicOr(&occ32[t * 8 + (hoct >> 1)], o | (op << 16));
  }
}

// Stage B+C fused: per-bf block stages cmp into registers, runs the 100-step
// refractory recurrence from occ in LDS, ANDs cmp with can into a TRANSPOSED
// [w][t] LDS layout so the expansion uses conflict-free ds_read_b128,
// then writes float4 output with nontemporal stores.
__global__ void __launch_bounds__(256) kern_out3(
    const u32* __restrict__ cmp32,   // [bf][t][8]
    const u32* __restrict__ occ32,   // [t][8]
    const float* __restrict__ ref0,
    float* __restrict__ out) {
  __shared__ u32 s_occ[T_STEPS * 8];
  __shared__ u32 s_can[T_STEPS * 8];
  __shared__ u32 s[8 * T_STEPS];     // [w][t] transposed
  const int bf = blockIdx.x;
  const int tid = threadIdx.x;

  // stage this bf's cmp slice (3200 B) into registers, coalesced uint4
  uint4 myc = make_uint4(0u, 0u, 0u, 0u);
  if (tid < 200) {
    myc = ((const uint4*)(cmp32 + (u64)bf * (T_STEPS * 8)))[tid];
    ((uint4*)s_occ)[tid] = ((const uint4*)occ32)[tid];
  }
  __syncthreads();

  {
    const int n = tid, lane = n & 63, v = n >> 6;
    float ref = ref0[n];
    for (int t = 0; t < T_STEPS; ++t) {
      bool can = (ref == 0.0f);
      u64 cm = __ballot(can);
      if (lane == 0) {
        s_can[t * 8 + v * 2]     = (u32)cm;
        s_can[t * 8 + v * 2 + 1] = (u32)(cm >> 32);
      }
      bool occb = (s_occ[t * 8 + (n >> 5)] >> (n & 31)) & 1u;
      bool occurred = can && occb;
      ref = fmaxf(ref - 1.0f, 0.0f) + (occurred ? 2.0f : 0.0f);
    }
  }
  __syncthreads();

  // AND + transpose into s[w*100 + t]
  if (tid < 200) {
    const int t = tid >> 1, w0 = (tid & 1) * 4;
    const u32* mp = (const u32*)&myc;
#pragma unroll
    for (int j = 0; j < 4; ++j) {
      s[(w0 + j) * T_STEPS + t] = mp[j] & s_can[t * 8 + w0 + j];
    }
  }
  __syncthreads();

  f32x4* outv = (f32x4*)(out + (u64)bf * (NNEUR * T_STEPS));
#pragma unroll
  for (int kk = 0; kk < 25; ++kk) {
    int q = tid + 256 * kk;          // float4 index within slice (6400 total)
    int e = q * 4;
    int n = e / 100;
    int t0 = e - n * 100;            // multiple of 4 (100 % 4 == 0)
    int bit = n & 31;
    uint4 wv = *(const uint4*)&s[(n >> 5) * T_STEPS + t0];  // ds_read_b128
    f32x4 val;
    val[0] = (float)((wv.x >> bit) & 1u);
    val[1] = (float)((wv.y >> bit) & 1u);
    val[2] = (float)((wv.z >> bit) & 1u);
    val[3] = (float)((wv.w >> bit) & 1u);
    __builtin_nontemporal_store(val, &outv[q]);
  }
}

// ---------------- fallback path (ws too small): round-1 working scheme ----
__global__ void __launch_bounds__(256) kern_bits_fb(
    const float* __restrict__ x, const float* __restrict__ c,
    const float* __restrict__ w, const float* __restrict__ a,
    const int* __restrict__ seedp,
    float* __restrict__ outf,
    u64* __restrict__ occ64) {
  const int t = blockIdx.x;
  const int chunk = blockIdx.y;
  const int lane = threadIdx.x & 63;
  const int v = threadIdx.x >> 6;
  const int n = v * 64 + lane;
  const u32 seed = (u32)seedp[0];
  u32 kt0 = 0u, kt1 = (u32)t;
  tf2x32(0u, seed, kt0, kt1);
  float cn = c[n], wn = w[n], an = a[n];
  bool occ = false;
  for (int j = 0; j < 64; ++j) {
    int bf = chunk * 64 + j;
    u32 i = (u32)(bf * 256 + n);
    u32 b0 = 0u, b1 = i;
    tf2x32(kt0, kt1, b0, b1);
    u32 bits = b0 ^ b1;
    float r = __uint_as_float((bits >> 9) | 0x3F800000u) - 1.0f;
    float d = x[bf] - cn;
    float denom = (2.0f * wn) * wn;
    float q = -(d * d) / denom;
    float pv = ((float)exp((double)q) * an) * 0.1f;
    bool cm = r < pv;
    occ |= cm;
    outf[(u64)bf * (NNEUR * T_STEPS) + (u64)n * T_STEPS + t] = cm ? 1.0f : 0.0f;
  }
  u64 om = __ballot(occ);
  if (lane == 0) atomicOr(&occ64[t * 4 + v], om);
}

__global__ void __launch_bounds__(256) kern_rec(
    const float* __restrict__ ref0,
    const u64* __restrict__ occ64,
    u64* __restrict__ can64) {
  int n = threadIdx.x;
  int lane = n & 63, v = n >> 6;
  float ref = ref0[n];
  for (int t = 0; t < T_STEPS; ++t) {
    bool can = (ref == 0.0f);
    u64 cm = __ballot(can);
    if (lane == 0) can64[t * 4 + v] = cm;
    bool occb = (occ64[t * 4 + v] >> lane) & 1ull;
    bool occurred = can && occb;
    ref = fmaxf(ref - 1.0f, 0.0f) + (occurred ? 2.0f : 0.0f);
  }
}

__global__ void __launch_bounds__(256) kern_mask(
    const u32* __restrict__ can32, float* __restrict__ out) {
  u64 q = (u64)blockIdx.x * 256 + threadIdx.x;
  float4* ov = (float4*)out;
  float4 vx = ov[q];
  u32 local = (u32)((q * 4) % (NNEUR * T_STEPS));
  float* vp = (float*)&vx;
#pragma unroll
  for (int j = 0; j < 4; ++j) {
    u32 le = local + j;
    u32 n = le / 100;
    u32 t = le - n * 100;
    u32 bit = (can32[t * 8 + (n >> 5)] >> (n & 31)) & 1u;
    vp[j] = bit ? vp[j] : 0.0f;
  }
  ov[q] = vx;
}

extern "C" void kernel_launch(void* const* d_in, const int* in_sizes, int n_in,
                              void* d_out, int out_size, void* d_ws, size_t ws_size,
                              hipStream_t stream) {
  const float* x  = (const float*)d_in[0];
  const float* c  = (const float*)d_in[1];
  const float* w  = (const float*)d_in[2];
  const float* a  = (const float*)d_in[3];
  const float* r0 = (const float*)d_in[4];
  const int* seed = (const int*)d_in[5];
  float* out = (float*)d_out;

  const size_t P_BYTES   = (size_t)NELEM * 4;                    // 2 MB thresholds
  const size_t CMP_BYTES = (size_t)NBF * T_STEPS * 4 * 8;        // 6.55 MB
  const size_t OCC_BYTES = (size_t)T_STEPS * 4 * 8;              // 3200 B
  const bool full = ws_size >= P_BYTES + CMP_BYTES + 2 * OCC_BYTES;

  uint8_t* wsb = (uint8_t*)d_ws;

  if (full) {
    u32* thr   = (u32*)wsb;
    u32* cmp   = (u32*)(wsb + P_BYTES);
    u32* occ   = (u32*)(wsb + P_BYTES + CMP_BYTES);
    kern_p<<<NELEM / 256, 256, 0, stream>>>(x, c, w, a, thr, occ);
    kern_bits3<<<dim3(T_STEPS, 128), 256, 0, stream>>>(thr, seed, cmp, occ);
    kern_out3<<<NBF, 256, 0, stream>>>(cmp, occ, r0, out);
  } else {
    u64* occ = (u64*)wsb;
    u64* can = (u64*)(wsb + OCC_BYTES);
    hipMemsetAsync(occ, 0, OCC_BYTES, stream);
    kern_bits_fb<<<dim3(T_STEPS, 32), 256, 0, stream>>>(x, c, w, a, seed, out, occ);
    kern_rec<<<1, 256, 0, stream>>>(r0, occ, can);
    kern_mask<<<(out_size / 4) / 256, 256, 0, stream>>>((const u32*)can, out);
  }
}